// Round 7
// baseline (1303.888 us; speedup 1.0000x reference)
//
#include <hip/hip_runtime.h>

#define TT 512

typedef __attribute__((ext_vector_type(8))) short bf16x8;
typedef __attribute__((ext_vector_type(4))) short s16x4;
typedef __attribute__((ext_vector_type(4))) float f32x4;

__device__ inline short f2bf(float f) {
    // round-to-nearest-even fp32 -> bf16 (values bounded; no NaN path needed)
    unsigned u = __float_as_uint(f);
    u += 0x7FFFu + ((u >> 16) & 1u);
    return (short)(u >> 16);
}

#define MFMA16(a, b, c) __builtin_amdgcn_mfma_f32_16x16x32_bf16((a), (b), (c), 0, 0, 0)

// 768 threads = 12 waves = 3 layers x 4 unit-quarters (16 units each).
// WG owns 2 batch rows; grid = 512 = 2 WG/CU TARGET. R2/R3's co-residency
// failure was the UNIFIED VGPR+AGPR budget (~104/wave -> 4 waves/SIMD cap ->
// 16 waves/CU < 24), NOT LDS. This version fits 6 waves/SIMD (<=85 regs):
//   - bias frags (16 AGPRs) -> 4 scalar biases + post-adds, zf4-seeded accs
//   - pairwise A-frag reuse: 8 regs instead of 16 (latency hidden by TLP)
//   - one shared 'ai' reg doubles as L0's exec-masked x frag (zeroed once)
//   - __launch_bounds__(768, 6) pins the allocator to the 85-reg budget
// A-frag rows replicated 8x (A row r = batch row r>>3): lane's C reg 0 =
// its own (batchrow=q>>1, unit=n_) preactivation. Gate transcendentals via
// exp2: r/z weights pre-scaled by -log2e, n-gate by 2*log2e (R5/R6 numerics).
__global__ __launch_bounds__(768, 6)
void gru_fused(const float* __restrict__ x,
               const float* __restrict__ Wih0, const float* __restrict__ Whh0,
               const float* __restrict__ bih0, const float* __restrict__ bhh0,
               const float* __restrict__ Wih1, const float* __restrict__ Whh1,
               const float* __restrict__ b_ih1, const float* __restrict__ b_hh1,
               const float* __restrict__ Wih2, const float* __restrict__ Whh2,
               const float* __restrict__ bih2, const float* __restrict__ bhh2,
               const float* __restrict__ fc1w, const float* __restrict__ fc1b,
               const float* __restrict__ fc2w, const float* __restrict__ fc2b,
               float* __restrict__ out)
{
    // x as bf16: [t][row][16], unpadded (32 KiB). Layer-0 A-frags exec-masked q<2.
    __shared__ __align__(16) short xls[TT][2][16];
    // h double buffers: row stride 80 shorts; pads never read.
    __shared__ __align__(16) short hbuf[3][2][2 * 80];
    __shared__ float h2out[2][64];
    __shared__ float fcz[2][32];

    const int tid = threadIdx.x;
    const int l   = tid & 63;
    const int wid = tid >> 6;                       // 0..11
    const int Ls  = __builtin_amdgcn_readfirstlane(wid >> 2);  // layer 0..2 (scalar)
    const int qt  = wid & 3;                        // unit quarter
    const int n_  = l & 15;                         // A/C col | B col
    const int q   = l >> 4;                         // quad
    const int ar  = n_ >> 3;                        // replicated A row -> batch row (0..1)
    const int rbase = blockIdx.x * 2;
    const int grow = q >> 1;                        // this lane's batch row (0..1)
    const int dup  = q & 1;                         // duplicate-lane flag
    const int u    = qt * 16 + n_;                  // this lane's h unit 0..63

    // ---- LDS init: hbuf = 0 (h(-1)=0) ----
    for (int i = tid; i < 3 * 2 * 160; i += 768) (&hbuf[0][0][0])[i] = 0;

    // ---- stage all x for this WG's 2 rows (float4 loads, 3 in flight) ----
    {
        const float4* xv = (const float4*)(x + (size_t)rbase * (TT * 16));
        auto stash = [&](int i, float4 v) {
            const int row = i >> 11, rem = i & 2047;    // 2048 float4 per row
            s16x4 pv = { f2bf(v.x), f2bf(v.y), f2bf(v.z), f2bf(v.w) };
            *(s16x4*)&xls[rem >> 2][row][(rem & 3) * 4] = pv;
        };
        for (int base = tid; base < 4096; base += 2304) {
            const int i1 = base + 768, i2 = base + 1536;
            const bool p1 = i1 < 4096, p2 = i2 < 4096;
            float4 v0 = xv[base], v1, v2;
            if (p1) v1 = xv[i1];
            if (p2) v2 = xv[i2];
            stash(base, v0);
            if (p1) stash(i1, v1);
            if (p2) stash(i2, v2);
        }
    }

    // ---- per-wave weight selection ----
    const float* Wih = (Ls == 0) ? Wih0 : (Ls == 1) ? Wih1 : Wih2;
    const float* Whh = (Ls == 0) ? Whh0 : (Ls == 1) ? Whh1 : Whh2;
    const float* bih = (Ls == 0) ? bih0 : (Ls == 1) ? b_ih1 : bih2;
    const float* bhh = (Ls == 0) ? bhh0 : (Ls == 1) ? b_hh1 : bhh2;
    const int ldih = (Ls == 0) ? 16 : 64;   // W_ih0 is [192,16]; K zero-padded

    const float L2E = 1.44269504088896f;

    // ---- resident B-frags: gate g in {0=r,1=z,2=n}, cols g*64+qt*16.. ----
    // B-frag lane layout: col = n_, k = kt*32 + q*8 + j. Gate scale folded in.
    bf16x8 wihf[3][2], whhf[3][2];
#pragma unroll
    for (int g = 0; g < 3; ++g) {
        const int gc = g * 64 + qt * 16;
        const float sc = (g < 2) ? -L2E : 2.0f * L2E;
#pragma unroll
        for (int kt = 0; kt < 2; ++kt) {
            const int kb = kt * 32 + q * 8;
            bf16x8 fi, fh;
#pragma unroll
            for (int j = 0; j < 8; ++j) {
                const int k = kb + j;
                float vi = (k < ldih) ? Wih[(gc + n_) * ldih + k] : 0.0f;
                float vh = Whh[(gc + n_) * 64 + k];
                fi[j] = f2bf(vi * sc);
                fh[j] = f2bf(vh * sc);
            }
            wihf[g][kt] = fi;
            whhf[g][kt] = fh;
        }
    }

    // ---- scalar gate biases (pre-scaled), added post-MFMA ----
    const float br  = -L2E * (bih[u] + bhh[u]);
    const float bz  = -L2E * (bih[64 + u] + bhh[64 + u]);
    const float bxn = 2.0f * L2E * bih[128 + u];
    const float bhn = 2.0f * L2E * bhh[128 + u];

    const f32x4 zf4 = {0.f, 0.f, 0.f, 0.f};
    // 'ai' doubles as L0's masked x-frag: q>=2 lanes zeroed ONCE, never rewritten
    bf16x8 ai = {0,0,0,0,0,0,0,0};

    float hp = 0.0f;   // this lane's h(row=grow, unit=u), carried fp32
    __syncthreads();

    // ---- pipelined time loop: wave of layer L processes t = s - L ----
    // x2 unroll so buffer parity is per-copy constant. Pairwise A-frag loads
    // (K-half 0 then K-half 1 into the SAME regs) cap live A-regs at 8.
#define GRU_STEP(sv, par)                                                        \
    {                                                                            \
        const int tw = (sv) - Ls;                                                \
        if (tw >= 0 && tw < TT) {                                                \
            const int bi = (par) ^ (Ls & 1);                                     \
            const short* own = &hbuf[Ls][bi ^ 1][0];                             \
            f32x4 cr, cz, cin, chn;                                              \
            if (Ls == 0) {                                                       \
                if (q < 2) ai = *(const bf16x8*)(&xls[tw][ar][q * 8]);           \
                bf16x8 ah = *(const bf16x8*)(own + ar * 80 + q * 8);             \
                cr  = MFMA16(ah, whhf[0][0], zf4);                               \
                cz  = MFMA16(ah, whhf[1][0], zf4);                               \
                chn = MFMA16(ah, whhf[2][0], zf4);                               \
                cr  = MFMA16(ai, wihf[0][0], cr);                                \
                cz  = MFMA16(ai, wihf[1][0], cz);                                \
                cin = MFMA16(ai, wihf[2][0], zf4);                               \
                ah  = *(const bf16x8*)(own + ar * 80 + 32 + q * 8);              \
                cr  = MFMA16(ah, whhf[0][1], cr);                                \
                cz  = MFMA16(ah, whhf[1][1], cz);                                \
                chn = MFMA16(ah, whhf[2][1], chn);                               \
            } else {                                                             \
                const short* inp = &hbuf[Ls - 1][bi][0];                         \
                bf16x8 ah = *(const bf16x8*)(own + ar * 80 + q * 8);             \
                ai  = *(const bf16x8*)(inp + ar * 80 + q * 8);                   \
                cr  = MFMA16(ah, whhf[0][0], zf4);                               \
                cz  = MFMA16(ah, whhf[1][0], zf4);                               \
                chn = MFMA16(ah, whhf[2][0], zf4);                               \
                cr  = MFMA16(ai, wihf[0][0], cr);                                \
                cz  = MFMA16(ai, wihf[1][0], cz);                                \
                cin = MFMA16(ai, wihf[2][0], zf4);                               \
                ah  = *(const bf16x8*)(own + ar * 80 + 32 + q * 8);              \
                ai  = *(const bf16x8*)(inp + ar * 80 + 32 + q * 8);              \
                cr  = MFMA16(ah, whhf[0][1], cr);                                \
                cz  = MFMA16(ah, whhf[1][1], cz);                                \
                chn = MFMA16(ah, whhf[2][1], chn);                               \
                cr  = MFMA16(ai, wihf[0][1], cr);                                \
                cz  = MFMA16(ai, wihf[1][1], cz);                                \
                cin = MFMA16(ai, wihf[2][1], cin);                               \
            }                                                                    \
            const float pr = cr[0] + br;                                         \
            const float pz = cz[0] + bz;                                         \
            const float rr = __fdividef(1.0f, 1.0f + exp2f(pr));                 \
            const float zz = __fdividef(1.0f, 1.0f + exp2f(pz));                 \
            const float sn = (cin[0] + bxn) + rr * (chn[0] + bhn);               \
            const float nn = 1.0f - __fdividef(2.0f, 1.0f + exp2f(sn));          \
            const float hv = nn + zz * (hp - nn);                                \
            hp = hv;                                                             \
            if (!dup) hbuf[Ls][bi][grow * 80 + u] = f2bf(hv);                    \
        }                                                                        \
        __syncthreads();                                                         \
    }

    for (int s0 = 0; s0 < TT + 2; s0 += 2) {
        GRU_STEP(s0, 0)
        GRU_STEP(s0 + 1, 1)
    }
#undef GRU_STEP

    // ---- FC head: layer-2 waves hold h2(T-1), one value per lane ----
    if (wid >= 8 && !dup) h2out[grow][u] = hp;
    __syncthreads();
    if (tid < 64) {
        const int row = tid >> 5, uu = tid & 31;
        float acc = fc1b[uu];
#pragma unroll
        for (int k = 0; k < 64; ++k) acc += h2out[row][k] * fc1w[uu * 64 + k];
        fcz[row][uu] = fmaxf(acc, 0.0f);
    }
    __syncthreads();
    if (tid < 2) {
        float y = fc2b[0];
#pragma unroll
        for (int uu = 0; uu < 32; ++uu) y += fcz[tid][uu] * fc2w[uu];
        out[rbase + tid] = y;
    }
}

extern "C" void kernel_launch(void* const* d_in, const int* in_sizes, int n_in,
                              void* d_out, int out_size, void* d_ws, size_t ws_size,
                              hipStream_t stream) {
    (void)in_sizes; (void)n_in; (void)d_ws; (void)ws_size; (void)out_size;
    gru_fused<<<dim3(512), dim3(768), 0, stream>>>(
        (const float*)d_in[0],
        (const float*)d_in[1],  (const float*)d_in[2],  (const float*)d_in[3],  (const float*)d_in[4],
        (const float*)d_in[5],  (const float*)d_in[6],  (const float*)d_in[7],  (const float*)d_in[8],
        (const float*)d_in[9],  (const float*)d_in[10], (const float*)d_in[11], (const float*)d_in[12],
        (const float*)d_in[13], (const float*)d_in[14], (const float*)d_in[15], (const float*)d_in[16],
        (float*)d_out);
}